// Round 1
// baseline (306.442 us; speedup 1.0000x reference)
//
#include <hip/hip_runtime.h>

#define NN 16384
#define CC 64
#define BB 32

typedef __attribute__((ext_vector_type(8))) short bf16x8;
typedef __attribute__((ext_vector_type(4))) short bf16x4;
typedef __attribute__((ext_vector_type(4))) float f32x4;
typedef __attribute__((ext_vector_type(16))) float f32x16;

__device__ __forceinline__ unsigned short f2bf(float f) {
    unsigned int u = __float_as_uint(f);
    unsigned int r = (u + 0x7fffu + ((u >> 16) & 1u)) >> 16;
    return (unsigned short)r;
}

__device__ __forceinline__ bf16x8 cvt8(float4 a, float4 b) {
    union { bf16x8 v; unsigned short s[8]; } u;
    u.s[0] = f2bf(a.x); u.s[1] = f2bf(a.y); u.s[2] = f2bf(a.z); u.s[3] = f2bf(a.w);
    u.s[4] = f2bf(b.x); u.s[5] = f2bf(b.y); u.s[6] = f2bf(b.z); u.s[7] = f2bf(b.w);
    return u.v;
}

// ---------------- K1: per-batch Gram partials + bf16 image emit ----------------
// grid = BB*8 blocks, 512 threads (8 waves). Block (b,chunk): cols chunk*2048..+2048,
// wave w covers 256 cols. Per-wave LDS partial (64x68 padded), parallel reduce,
// coalesced store to Gp[b][chunk][4096].
// NEW: each fragment register is also stored to Xbf (bf16 x, same layout as x) so
// k_out never touches the f32 input again. Store pattern: per inst, 4 quads cover
// 64 B contiguous per row x 16 rows -> sector-sized segments.
#define GP 68  // float pitch: bank stride (4*GP/4)%32 = 4 -> scattered writes 2-way = free
__global__ __launch_bounds__(512) void k_gram(const float* __restrict__ x,
                                              float* __restrict__ Gp,
                                              unsigned short* __restrict__ Xbf) {
    int b = blockIdx.x >> 3, chunk = blockIdx.x & 7;
    int wave = threadIdx.x >> 6, lane = threadIdx.x & 63;
    int lrow = lane & 15, quad = lane >> 4;
    const float* xb = x + (size_t)b * CC * NN;
    unsigned short* xo = Xbf + (size_t)b * CC * NN;
    int kbase = chunk * 2048 + wave * 256;

    __shared__ float Gw[8 * 64 * GP];  // 139264 B

    f32x4 acc[4][4] = {};
    for (int ks = 0; ks < 8; ++ks) {
        int k0 = kbase + ks * 32 + quad * 8;
        bf16x8 fr[4];
        #pragma unroll
        for (int ti = 0; ti < 4; ++ti) {
            const float* p = xb + (size_t)(16 * ti + lrow) * NN + k0;
            float4 a  = *(const float4*)p;
            float4 b4 = *(const float4*)(p + 4);
            fr[ti] = cvt8(a, b4);
        }
        // emit bf16 image (fire-and-forget; hides under the BW stall)
        #pragma unroll
        for (int ti = 0; ti < 4; ++ti)
            *(bf16x8*)(xo + (size_t)(16 * ti + lrow) * NN + k0) = fr[ti];
        #pragma unroll
        for (int mi = 0; mi < 4; ++mi)
            #pragma unroll
            for (int ni = 0; ni < 4; ++ni)
                acc[mi][ni] = __builtin_amdgcn_mfma_f32_16x16x32_bf16(
                    fr[mi], fr[ni], acc[mi][ni], 0, 0, 0);
    }

    float* gw = Gw + wave * 64 * GP;
    #pragma unroll
    for (int mi = 0; mi < 4; ++mi)
        #pragma unroll
        for (int ni = 0; ni < 4; ++ni)
            #pragma unroll
            for (int r = 0; r < 4; ++r) {
                int row = 16 * mi + quad * 4 + r;
                int col = 16 * ni + lrow;
                gw[row * GP + col] = acc[mi][ni][r];
            }
    __syncthreads();

    float* gp = Gp + ((size_t)b * 8 + chunk) * 4096;
    for (int i = threadIdx.x; i < 4096; i += 512) {
        int off = (i >> 6) * GP + (i & 63);
        float s = 0.f;
        #pragma unroll
        for (int w = 0; w < 8; ++w) s += Gw[w * 64 * GP + off];
        gp[i] = s;
    }
}

// ---------------- K2: fused sigma + G-reduce + A = (gamma/sigma)*G@W + I ----------------
// grid = BB blocks, 256 threads. Emits bf16 A-fragments pre-swizzled for
// mfma_f32_32x32x16_bf16 A-operand: value(ks,mi,lane,j) = A[32mi+(lane&31)][16ks+(lane>>5)*8+j]
__global__ __launch_bounds__(256) void k_build_A(const float* __restrict__ W,
                                                 const float* __restrict__ u,
                                                 const float* __restrict__ gamma,
                                                 const float* __restrict__ Gp,
                                                 unsigned short* __restrict__ Afrag) {
    int b = blockIdx.x;
    int tid = threadIdx.x;
    __shared__ float Ws[4096];
    __shared__ float Gs[64 * 65];
    __shared__ float As[64 * 68];
    __shared__ float us[64];
    __shared__ float gshare;

    for (int i = tid; i < 4096; i += 256) Ws[i] = W[i];
    if (tid < 64) us[tid] = u[tid];
    __syncthreads();

    // wave 0: spectral norm (one power iteration), fold 1/sigma into gamma
    if (tid < 64) {
        int c = tid;
        float t = 0.f;
        #pragma unroll 8
        for (int r = 0; r < 64; ++r) t += Ws[r * 64 + c] * us[r];
        float s = t * t;
        #pragma unroll
        for (int m = 1; m < 64; m <<= 1) s += __shfl_xor(s, m);
        float v = t / fmaxf(sqrtf(s), 1e-12f);
        float wv = 0.f;
        #pragma unroll 8
        for (int k = 0; k < 64; ++k) wv += Ws[c * 64 + k] * __shfl(v, k);
        float s2 = wv * wv;
        #pragma unroll
        for (int m = 1; m < 64; m <<= 1) s2 += __shfl_xor(s2, m);
        float nw = sqrtf(s2);
        float sigma = s2 / fmaxf(nw, 1e-12f);
        if (c == 0) gshare = gamma[0] / fmaxf(sigma, 1e-30f);
    }

    // all threads: reduce the 8 Gram partials (coalesced)
    const float* gp = Gp + (size_t)b * 8 * 4096;
    for (int i = tid; i < 4096; i += 256) {
        float s = 0.f;
        #pragma unroll
        for (int c = 0; c < 8; ++c) s += gp[c * 4096 + i];
        Gs[(i >> 6) * 65 + (i & 63)] = s;
    }
    __syncthreads();

    // A[r][c] = g2 * sum_k G[r][k] W[k][c] + (r==c)
    {
        int r = tid >> 2, j0 = (tid & 3) * 16;
        float a[16];
        #pragma unroll
        for (int j = 0; j < 16; ++j) a[j] = 0.f;
        for (int k = 0; k < 64; ++k) {
            float g = Gs[r * 65 + k];
            const float* wr = &Ws[k * 64 + j0];
            float4 w0 = *(const float4*)(wr);
            float4 w1 = *(const float4*)(wr + 4);
            float4 w2 = *(const float4*)(wr + 8);
            float4 w3 = *(const float4*)(wr + 12);
            a[0]  += g * w0.x; a[1]  += g * w0.y; a[2]  += g * w0.z; a[3]  += g * w0.w;
            a[4]  += g * w1.x; a[5]  += g * w1.y; a[6]  += g * w1.z; a[7]  += g * w1.w;
            a[8]  += g * w2.x; a[9]  += g * w2.y; a[10] += g * w2.z; a[11] += g * w2.w;
            a[12] += g * w3.x; a[13] += g * w3.y; a[14] += g * w3.z; a[15] += g * w3.w;
        }
        float g2 = gshare;
        #pragma unroll
        for (int j = 0; j < 16; ++j) {
            float vv = a[j] * g2 + ((r == j0 + j) ? 1.f : 0.f);
            As[r * 68 + j0 + j] = vv;
        }
    }
    __syncthreads();

    // emit pre-swizzled bf16 fragments
    unsigned short* Ab = Afrag + (size_t)b * 4096;
    for (int fv = tid; fv < 512; fv += 256) {
        int ks = fv >> 7, mi = (fv >> 6) & 1, lane = fv & 63;
        int row = 32 * mi + (lane & 31);
        int col = 16 * ks + (lane >> 5) * 8;
        float4 a4 = *(const float4*)&As[row * 68 + col];
        float4 b4 = *(const float4*)&As[row * 68 + col + 4];
        *(bf16x8*)(Ab + (size_t)fv * 8) = cvt8(a4, b4);
    }
}

// ---------------- K3: out_b = A_b @ X_b (bf16 MFMA 32x32x16) ----------------
// grid = BB*128 blocks, 256 threads (4 waves). Block tile: 64 rows x 128 cols.
// NEW: stages from the bf16 image (half the read bytes, L3-resident, no f2bf).
// Pack is a pure bit-OR of the two row values per k-pair (same bits as before).
#define PITCH 68  // shorts per XT row; write banks (2n+rp)%32 conflict-free, b64 reads balanced
__global__ __launch_bounds__(256) void k_out(const unsigned short* __restrict__ Xbf,
                                             const unsigned short* __restrict__ Afrag,
                                             float* __restrict__ out) {
    int nblk = blockIdx.x & 127;
    int b = blockIdx.x >> 7;
    int col0 = nblk * 128;
    int wave = threadIdx.x >> 6, lane = threadIdx.x & 63;
    const unsigned short* xb = Xbf + (size_t)b * CC * NN;

    __shared__ __align__(16) unsigned short XT[128 * PITCH]; // transposed tile [n][k]

    // stage + transpose: rp = row pair (0..31), nc = 16-col chunk (0..7)
    {
        int rp = threadIdx.x & 31;
        int nc = threadIdx.x >> 5;
        int r0 = rp * 2;
        int cs = nc * 16;
        const unsigned short* pr0 = xb + (size_t)r0 * NN + col0 + cs;
        const unsigned short* pr1 = pr0 + NN;
        union { bf16x8 v; unsigned short s[8]; } a0, a1, b0, b1;
        a0.v = *(const bf16x8*)(pr0);      // row r0,   cols cs..cs+8
        a1.v = *(const bf16x8*)(pr0 + 8);  // row r0,   cols cs+8..cs+16
        b0.v = *(const bf16x8*)(pr1);      // row r0+1, cols cs..cs+8
        b1.v = *(const bf16x8*)(pr1 + 8);  // row r0+1, cols cs+8..cs+16
        #pragma unroll
        for (int e = 0; e < 8; ++e) {
            *(unsigned int*)&XT[(cs + e) * PITCH + r0] =
                (unsigned)a0.s[e] | ((unsigned)b0.s[e] << 16);
            *(unsigned int*)&XT[(cs + 8 + e) * PITCH + r0] =
                (unsigned)a1.s[e] | ((unsigned)b1.s[e] << 16);
        }
    }

    // A fragments (pre-swizzled): 4 k-steps x 2 m-tiles
    bf16x8 af[4][2];
    const unsigned short* Ab = Afrag + (size_t)b * 4096;
    #pragma unroll
    for (int ks = 0; ks < 4; ++ks)
        #pragma unroll
        for (int mi = 0; mi < 2; ++mi)
            af[ks][mi] = *(const bf16x8*)(Ab + ((ks * 2 + mi) * 64 + lane) * 8);

    __syncthreads();

    f32x16 acc[2] = {};
    int n = wave * 32 + (lane & 31);
    int kh = (lane >> 5) * 8;
    #pragma unroll
    for (int ks = 0; ks < 4; ++ks) {
        union { bf16x8 v; bf16x4 h[2]; } bu;
        bu.h[0] = *(const bf16x4*)&XT[n * PITCH + ks * 16 + kh];
        bu.h[1] = *(const bf16x4*)&XT[n * PITCH + ks * 16 + kh + 4];
        acc[0] = __builtin_amdgcn_mfma_f32_32x32x16_bf16(af[ks][0], bu.v, acc[0], 0, 0, 0);
        acc[1] = __builtin_amdgcn_mfma_f32_32x32x16_bf16(af[ks][1], bu.v, acc[1], 0, 0, 0);
    }

    // store: D col = lane&31, row = (reg&3) + 8*(reg>>2) + 4*(lane>>5)
    float* ob = out + (size_t)b * CC * NN;
    int gcol = col0 + n;
    #pragma unroll
    for (int mi = 0; mi < 2; ++mi)
        #pragma unroll
        for (int r = 0; r < 16; ++r) {
            int grow = 32 * mi + (r & 3) + 8 * (r >> 2) + 4 * (lane >> 5);
            ob[(size_t)grow * NN + gcol] = acc[mi][r];
        }
}

extern "C" void kernel_launch(void* const* d_in, const int* in_sizes, int n_in,
                              void* d_out, int out_size, void* d_ws, size_t ws_size,
                              hipStream_t stream) {
    const float* x     = (const float*)d_in[0];
    const float* W     = (const float*)d_in[1];
    const float* gamma = (const float*)d_in[2];
    const float* u     = (const float*)d_in[3];
    float* out = (float*)d_out;

    char* ws = (char*)d_ws;
    float* Gp             = (float*)ws;                         // 32*8*4096*4 = 4 MB
    unsigned short* Afrag = (unsigned short*)(ws + (5 << 20));  // 256 KB
    unsigned short* Xbf   = (unsigned short*)(ws + (6 << 20));  // 32*64*16384*2 = 64 MB

    k_gram<<<BB * 8, 512, 0, stream>>>(x, Gp, Xbf);
    k_build_A<<<BB, 256, 0, stream>>>(W, u, gamma, Gp, Afrag);
    k_out<<<BB * 128, 256, 0, stream>>>(Xbf, Afrag, out);
}

// Round 2
// 287.497 us; speedup vs baseline: 1.0659x; 1.0659x over previous
//
#include <hip/hip_runtime.h>

#define NN 16384
#define CC 64
#define BB 32
#define NCH 32       // k-chunks per batch in k_gram
#define CHUNK 512    // cols per k_gram block
#define KSTAGE 128   // cols per LDS stage
#define XP 136       // LDS pitch in shorts (68 dwords -> conflict-free b64 writes / b128 reads)

typedef __attribute__((ext_vector_type(8))) short bf16x8;
typedef __attribute__((ext_vector_type(4))) short bf16x4;
typedef __attribute__((ext_vector_type(4))) float f32x4;
typedef __attribute__((ext_vector_type(16))) float f32x16;

__device__ __forceinline__ unsigned short f2bf(float f) {
    unsigned int u = __float_as_uint(f);
    unsigned int r = (u + 0x7fffu + ((u >> 16) & 1u)) >> 16;
    return (unsigned short)r;
}

__device__ __forceinline__ bf16x8 cvt8(float4 a, float4 b) {
    union { bf16x8 v; unsigned short s[8]; } u;
    u.s[0] = f2bf(a.x); u.s[1] = f2bf(a.y); u.s[2] = f2bf(a.z); u.s[3] = f2bf(a.w);
    u.s[4] = f2bf(b.x); u.s[5] = f2bf(b.y); u.s[6] = f2bf(b.z); u.s[7] = f2bf(b.w);
    return u.v;
}

// ---------------- K1: Gram via LDS-staged tiles, disjoint wave-owned outputs ----------
// grid = BB*32 = 1024 blocks, 512 threads (8 waves). Block (b,chunk): cols chunk*512..+512,
// 4 double-buffered stages of 128 cols. Staging converts f32->bf16 once, feeding both
// the LDS tile and the global bf16 image (Xbf) consumed by k_out.
// Each wave owns 2 of the 16 16x16 output tiles -> no cross-wave reduce, acc = 8 VGPRs.
// Partials: Gp[b][chunk][64*64], reduced in k_build_A.
__global__ __launch_bounds__(512, 6) void k_gram(const float* __restrict__ x,
                                                 float* __restrict__ Gp,
                                                 unsigned short* __restrict__ Xbf) {
    const int b = blockIdx.x >> 5, chunk = blockIdx.x & 31;
    const int t = threadIdx.x;
    const int lane = t & 63;
    const int lrow = lane & 15, quad = lane >> 4;
    const int wave = t >> 6;
    const int mi = wave >> 1, ni0 = (wave & 1) * 2;

    const float* xb = x + (size_t)b * CC * NN;
    unsigned short* xo = Xbf + (size_t)b * CC * NN;
    const int kbase = chunk * CHUNK;

    // staging map: thread covers rows r0+16i (i=0..3), cols c4*4..+4 of the stage
    const int r0 = t >> 5, c4 = t & 31;

    __shared__ __align__(16) unsigned short Xs[2][64 * XP]; // 2 x 17408 B = 34816 B

    float4 sv0, sv1, sv2, sv3;

#define LOADS(s)                                                                  \
    {                                                                             \
        const float* p = xb + kbase + (s) * KSTAGE + c4 * 4;                      \
        sv0 = *(const float4*)(p + (size_t)(r0)      * NN);                       \
        sv1 = *(const float4*)(p + (size_t)(r0 + 16) * NN);                       \
        sv2 = *(const float4*)(p + (size_t)(r0 + 32) * NN);                       \
        sv3 = *(const float4*)(p + (size_t)(r0 + 48) * NN);                       \
    }

#define WRITES(s)                                                                 \
    {                                                                             \
        unsigned short* bp = &Xs[(s) & 1][0];                                     \
        const float4 vv[4] = {sv0, sv1, sv2, sv3};                                \
        _Pragma("unroll")                                                         \
        for (int i = 0; i < 4; ++i) {                                             \
            unsigned int lo = (unsigned)f2bf(vv[i].x) | ((unsigned)f2bf(vv[i].y) << 16); \
            unsigned int hi = (unsigned)f2bf(vv[i].z) | ((unsigned)f2bf(vv[i].w) << 16); \
            uint2 pk = make_uint2(lo, hi);                                        \
            *(uint2*)&bp[(r0 + 16 * i) * XP + c4 * 4] = pk;                       \
            *(uint2*)(xo + (size_t)(r0 + 16 * i) * NN + kbase + (s) * KSTAGE + c4 * 4) = pk; \
        }                                                                         \
    }

    f32x4 acc0 = {}, acc1 = {};

#define COMPUTE(s)                                                                \
    {                                                                             \
        const unsigned short* bp = &Xs[(s) & 1][0];                               \
        _Pragma("unroll")                                                         \
        for (int ks = 0; ks < 4; ++ks) {                                          \
            int kcol = ks * 32 + quad * 8;                                        \
            bf16x8 fa  = *(const bf16x8*)&bp[(16 * mi        + lrow) * XP + kcol];\
            bf16x8 fb0 = *(const bf16x8*)&bp[(16 * ni0       + lrow) * XP + kcol];\
            bf16x8 fb1 = *(const bf16x8*)&bp[(16 * (ni0 + 1) + lrow) * XP + kcol];\
            acc0 = __builtin_amdgcn_mfma_f32_16x16x32_bf16(fa, fb0, acc0, 0, 0, 0);\
            acc1 = __builtin_amdgcn_mfma_f32_16x16x32_bf16(fa, fb1, acc1, 0, 0, 0);\
        }                                                                         \
    }

    // prologue
    LOADS(0);
    WRITES(0);
    __syncthreads();

    #pragma unroll
    for (int s = 0; s < 4; ++s) {
        if (s < 3) LOADS(s + 1);       // issue early; latency hides under compute
        COMPUTE(s);
        if (s < 3) WRITES(s + 1);      // writes the other buffer
        __syncthreads();
    }

    // epilogue: store wave-owned tiles to the per-chunk partial
    float* gp = Gp + ((size_t)b * NCH + chunk) * 4096;
    #pragma unroll
    for (int r = 0; r < 4; ++r) {
        int row = 16 * mi + quad * 4 + r;
        gp[row * 64 + 16 * ni0 + lrow]        = acc0[r];
        gp[row * 64 + 16 * (ni0 + 1) + lrow]  = acc1[r];
    }
#undef LOADS
#undef WRITES
#undef COMPUTE
}

// ---------------- K2: fused sigma + G-reduce + A = (gamma/sigma)*G@W + I ----------------
// grid = BB blocks, 256 threads. Emits bf16 A-fragments pre-swizzled for
// mfma_f32_32x32x16_bf16 A-operand: value(ks,mi,lane,j) = A[32mi+(lane&31)][16ks+(lane>>5)*8+j]
__global__ __launch_bounds__(256) void k_build_A(const float* __restrict__ W,
                                                 const float* __restrict__ u,
                                                 const float* __restrict__ gamma,
                                                 const float* __restrict__ Gp,
                                                 unsigned short* __restrict__ Afrag) {
    int b = blockIdx.x;
    int tid = threadIdx.x;
    __shared__ float Ws[4096];
    __shared__ float Gs[64 * 65];
    __shared__ float As[64 * 68];
    __shared__ float us[64];
    __shared__ float gshare;

    for (int i = tid; i < 4096; i += 256) Ws[i] = W[i];
    if (tid < 64) us[tid] = u[tid];
    __syncthreads();

    // wave 0: spectral norm (one power iteration), fold 1/sigma into gamma
    if (tid < 64) {
        int c = tid;
        float t = 0.f;
        #pragma unroll 8
        for (int r = 0; r < 64; ++r) t += Ws[r * 64 + c] * us[r];
        float s = t * t;
        #pragma unroll
        for (int m = 1; m < 64; m <<= 1) s += __shfl_xor(s, m);
        float v = t / fmaxf(sqrtf(s), 1e-12f);
        float wv = 0.f;
        #pragma unroll 8
        for (int k = 0; k < 64; ++k) wv += Ws[c * 64 + k] * __shfl(v, k);
        float s2 = wv * wv;
        #pragma unroll
        for (int m = 1; m < 64; m <<= 1) s2 += __shfl_xor(s2, m);
        float nw = sqrtf(s2);
        float sigma = s2 / fmaxf(nw, 1e-12f);
        if (c == 0) gshare = gamma[0] / fmaxf(sigma, 1e-30f);
    }

    // all threads: reduce the 32 Gram partials (coalesced)
    const float* gp = Gp + (size_t)b * NCH * 4096;
    for (int i = tid; i < 4096; i += 256) {
        float s = 0.f;
        #pragma unroll
        for (int c = 0; c < NCH; ++c) s += gp[c * 4096 + i];
        Gs[(i >> 6) * 65 + (i & 63)] = s;
    }
    __syncthreads();

    // A[r][c] = g2 * sum_k G[r][k] W[k][c] + (r==c)
    {
        int r = tid >> 2, j0 = (tid & 3) * 16;
        float a[16];
        #pragma unroll
        for (int j = 0; j < 16; ++j) a[j] = 0.f;
        for (int k = 0; k < 64; ++k) {
            float g = Gs[r * 65 + k];
            const float* wr = &Ws[k * 64 + j0];
            float4 w0 = *(const float4*)(wr);
            float4 w1 = *(const float4*)(wr + 4);
            float4 w2 = *(const float4*)(wr + 8);
            float4 w3 = *(const float4*)(wr + 12);
            a[0]  += g * w0.x; a[1]  += g * w0.y; a[2]  += g * w0.z; a[3]  += g * w0.w;
            a[4]  += g * w1.x; a[5]  += g * w1.y; a[6]  += g * w1.z; a[7]  += g * w1.w;
            a[8]  += g * w2.x; a[9]  += g * w2.y; a[10] += g * w2.z; a[11] += g * w2.w;
            a[12] += g * w3.x; a[13] += g * w3.y; a[14] += g * w3.z; a[15] += g * w3.w;
        }
        float g2 = gshare;
        #pragma unroll
        for (int j = 0; j < 16; ++j) {
            float vv = a[j] * g2 + ((r == j0 + j) ? 1.f : 0.f);
            As[r * 68 + j0 + j] = vv;
        }
    }
    __syncthreads();

    // emit pre-swizzled bf16 fragments
    unsigned short* Ab = Afrag + (size_t)b * 4096;
    for (int fv = tid; fv < 512; fv += 256) {
        int ks = fv >> 7, mi = (fv >> 6) & 1, lane = fv & 63;
        int row = 32 * mi + (lane & 31);
        int col = 16 * ks + (lane >> 5) * 8;
        float4 a4 = *(const float4*)&As[row * 68 + col];
        float4 b4 = *(const float4*)&As[row * 68 + col + 4];
        *(bf16x8*)(Ab + (size_t)fv * 8) = cvt8(a4, b4);
    }
}

// ---------------- K3: out_b = A_b @ X_b (bf16 MFMA 32x32x16) ----------------
// grid = BB*128 blocks, 256 threads (4 waves). Block tile: 64 rows x 128 cols.
// Stages from the bf16 image (half the read bytes, L3-friendly, no f2bf).
#define PITCH 68  // shorts per XT row
__global__ __launch_bounds__(256) void k_out(const unsigned short* __restrict__ Xbf,
                                             const unsigned short* __restrict__ Afrag,
                                             float* __restrict__ out) {
    int nblk = blockIdx.x & 127;
    int b = blockIdx.x >> 7;
    int col0 = nblk * 128;
    int wave = threadIdx.x >> 6, lane = threadIdx.x & 63;
    const unsigned short* xb = Xbf + (size_t)b * CC * NN;

    __shared__ __align__(16) unsigned short XT[128 * PITCH]; // transposed tile [n][k]

    // stage + transpose: rp = row pair (0..31), nc = 16-col chunk (0..7)
    {
        int rp = threadIdx.x & 31;
        int nc = threadIdx.x >> 5;
        int r0 = rp * 2;
        int cs = nc * 16;
        const unsigned short* pr0 = xb + (size_t)r0 * NN + col0 + cs;
        const unsigned short* pr1 = pr0 + NN;
        union { bf16x8 v; unsigned short s[8]; } a0, a1, b0, b1;
        a0.v = *(const bf16x8*)(pr0);      // row r0,   cols cs..cs+8
        a1.v = *(const bf16x8*)(pr0 + 8);  // row r0,   cols cs+8..cs+16
        b0.v = *(const bf16x8*)(pr1);      // row r0+1, cols cs..cs+8
        b1.v = *(const bf16x8*)(pr1 + 8);  // row r0+1, cols cs+8..cs+16
        #pragma unroll
        for (int e = 0; e < 8; ++e) {
            *(unsigned int*)&XT[(cs + e) * PITCH + r0] =
                (unsigned)a0.s[e] | ((unsigned)b0.s[e] << 16);
            *(unsigned int*)&XT[(cs + 8 + e) * PITCH + r0] =
                (unsigned)a1.s[e] | ((unsigned)b1.s[e] << 16);
        }
    }

    // A fragments (pre-swizzled): 4 k-steps x 2 m-tiles
    bf16x8 af[4][2];
    const unsigned short* Ab = Afrag + (size_t)b * 4096;
    #pragma unroll
    for (int ks = 0; ks < 4; ++ks)
        #pragma unroll
        for (int mi = 0; mi < 2; ++mi)
            af[ks][mi] = *(const bf16x8*)(Ab + ((ks * 2 + mi) * 64 + lane) * 8);

    __syncthreads();

    f32x16 acc[2] = {};
    int n = wave * 32 + (lane & 31);
    int kh = (lane >> 5) * 8;
    #pragma unroll
    for (int ks = 0; ks < 4; ++ks) {
        union { bf16x8 v; bf16x4 h[2]; } bu;
        bu.h[0] = *(const bf16x4*)&XT[n * PITCH + ks * 16 + kh];
        bu.h[1] = *(const bf16x4*)&XT[n * PITCH + ks * 16 + kh + 4];
        acc[0] = __builtin_amdgcn_mfma_f32_32x32x16_bf16(af[ks][0], bu.v, acc[0], 0, 0, 0);
        acc[1] = __builtin_amdgcn_mfma_f32_32x32x16_bf16(af[ks][1], bu.v, acc[1], 0, 0, 0);
    }

    // store: D col = lane&31, row = (reg&3) + 8*(reg>>2) + 4*(lane>>5)
    float* ob = out + (size_t)b * CC * NN;
    int gcol = col0 + n;
    #pragma unroll
    for (int mi = 0; mi < 2; ++mi)
        #pragma unroll
        for (int r = 0; r < 16; ++r) {
            int grow = 32 * mi + (r & 3) + 8 * (r >> 2) + 4 * (lane >> 5);
            ob[(size_t)grow * NN + gcol] = acc[mi][r];
        }
}

extern "C" void kernel_launch(void* const* d_in, const int* in_sizes, int n_in,
                              void* d_out, int out_size, void* d_ws, size_t ws_size,
                              hipStream_t stream) {
    const float* x     = (const float*)d_in[0];
    const float* W     = (const float*)d_in[1];
    const float* gamma = (const float*)d_in[2];
    const float* u     = (const float*)d_in[3];
    float* out = (float*)d_out;

    char* ws = (char*)d_ws;
    float* Gp             = (float*)ws;                          // 32*32*4096*4 = 16 MB
    unsigned short* Afrag = (unsigned short*)(ws + (16 << 20));  // 256 KB
    unsigned short* Xbf   = (unsigned short*)(ws + (17 << 20));  // 64 MB

    k_gram<<<BB * NCH, 512, 0, stream>>>(x, Gp, Xbf);
    k_build_A<<<BB, 256, 0, stream>>>(W, u, gamma, Gp, Afrag);
    k_out<<<BB * 128, 256, 0, stream>>>(Xbf, Afrag, out);
}

// Round 3
// 279.009 us; speedup vs baseline: 1.0983x; 1.0304x over previous
//
#include <hip/hip_runtime.h>

#define NN 16384
#define CC 64
#define BB 32
#define NCH 32       // k-chunks per batch in k_gram
#define CHUNK 512    // cols per k_gram block
#define KSTAGE 128   // cols per LDS stage
#define XP 136       // LDS pitch in shorts (68 dwords -> conflict-free b64 writes / b128 reads)

typedef __attribute__((ext_vector_type(8))) short bf16x8;
typedef __attribute__((ext_vector_type(4))) short bf16x4;
typedef __attribute__((ext_vector_type(4))) float f32x4;
typedef __attribute__((ext_vector_type(16))) float f32x16;

__device__ __forceinline__ unsigned short f2bf(float f) {
    unsigned int u = __float_as_uint(f);
    unsigned int r = (u + 0x7fffu + ((u >> 16) & 1u)) >> 16;
    return (unsigned short)r;
}

__device__ __forceinline__ bf16x8 cvt8(float4 a, float4 b) {
    union { bf16x8 v; unsigned short s[8]; } u;
    u.s[0] = f2bf(a.x); u.s[1] = f2bf(a.y); u.s[2] = f2bf(a.z); u.s[3] = f2bf(a.w);
    u.s[4] = f2bf(b.x); u.s[5] = f2bf(b.y); u.s[6] = f2bf(b.z); u.s[7] = f2bf(b.w);
    return u.v;
}

// ---------------- K1: Gram via LDS-staged tiles, disjoint wave-owned outputs ----------
// grid = BB*32 = 1024 blocks, 512 threads (8 waves). Block (b,chunk): cols chunk*512..+512,
// 4 double-buffered stages of 128 cols. Staging converts f32->bf16 once into LDS only
// (NO global bf16 emit: store-drain on recycled data VGPRs serialized the pipeline in r1/r2,
// and k_out can re-read f32 x from L3 for free since x is L3-resident).
// Each wave owns 2 of the 16 16x16 output tiles -> no cross-wave reduce, acc = 8 VGPRs.
// Partials: Gp[b][chunk][64*64], reduced in k_build_A.
__global__ __launch_bounds__(512) void k_gram(const float* __restrict__ x,
                                              float* __restrict__ Gp) {
    const int b = blockIdx.x >> 5, chunk = blockIdx.x & 31;
    const int t = threadIdx.x;
    const int lane = t & 63;
    const int lrow = lane & 15, quad = lane >> 4;
    const int wave = t >> 6;
    const int mi = wave >> 1, ni0 = (wave & 1) * 2;

    const float* xb = x + (size_t)b * CC * NN;
    const int kbase = chunk * CHUNK;

    // staging map: thread covers rows r0+16i (i=0..3), cols c4*4..+4 of the stage
    const int r0 = t >> 5, c4 = t & 31;

    __shared__ __align__(16) unsigned short Xs[2][64 * XP]; // 2 x 17408 B = 34816 B

    float4 sv0, sv1, sv2, sv3;

#define LOADS(s)                                                                  \
    {                                                                             \
        const float* p = xb + kbase + (s) * KSTAGE + c4 * 4;                      \
        sv0 = *(const float4*)(p + (size_t)(r0)      * NN);                       \
        sv1 = *(const float4*)(p + (size_t)(r0 + 16) * NN);                       \
        sv2 = *(const float4*)(p + (size_t)(r0 + 32) * NN);                       \
        sv3 = *(const float4*)(p + (size_t)(r0 + 48) * NN);                       \
    }

#define WRITES(s)                                                                 \
    {                                                                             \
        unsigned short* bp = &Xs[(s) & 1][0];                                     \
        const float4 vv[4] = {sv0, sv1, sv2, sv3};                                \
        _Pragma("unroll")                                                         \
        for (int i = 0; i < 4; ++i) {                                             \
            unsigned int lo = (unsigned)f2bf(vv[i].x) | ((unsigned)f2bf(vv[i].y) << 16); \
            unsigned int hi = (unsigned)f2bf(vv[i].z) | ((unsigned)f2bf(vv[i].w) << 16); \
            *(uint2*)&bp[(r0 + 16 * i) * XP + c4 * 4] = make_uint2(lo, hi);       \
        }                                                                         \
    }

    f32x4 acc0 = {}, acc1 = {};

#define COMPUTE(s)                                                                \
    {                                                                             \
        const unsigned short* bp = &Xs[(s) & 1][0];                               \
        _Pragma("unroll")                                                         \
        for (int ks = 0; ks < 4; ++ks) {                                          \
            int kcol = ks * 32 + quad * 8;                                        \
            bf16x8 fa  = *(const bf16x8*)&bp[(16 * mi        + lrow) * XP + kcol];\
            bf16x8 fb0 = *(const bf16x8*)&bp[(16 * ni0       + lrow) * XP + kcol];\
            bf16x8 fb1 = *(const bf16x8*)&bp[(16 * (ni0 + 1) + lrow) * XP + kcol];\
            acc0 = __builtin_amdgcn_mfma_f32_16x16x32_bf16(fa, fb0, acc0, 0, 0, 0);\
            acc1 = __builtin_amdgcn_mfma_f32_16x16x32_bf16(fa, fb1, acc1, 0, 0, 0);\
        }                                                                         \
    }

    // prologue
    LOADS(0);
    WRITES(0);
    __syncthreads();

    #pragma unroll
    for (int s = 0; s < 4; ++s) {
        if (s < 3) LOADS(s + 1);       // issue early; latency hides under compute
        COMPUTE(s);
        if (s < 3) WRITES(s + 1);      // writes the other buffer
        __syncthreads();
    }

    // epilogue: store wave-owned tiles to the per-chunk partial
    float* gp = Gp + ((size_t)b * NCH + chunk) * 4096;
    #pragma unroll
    for (int r = 0; r < 4; ++r) {
        int row = 16 * mi + quad * 4 + r;
        gp[row * 64 + 16 * ni0 + lrow]        = acc0[r];
        gp[row * 64 + 16 * (ni0 + 1) + lrow]  = acc1[r];
    }
#undef LOADS
#undef WRITES
#undef COMPUTE
}

// ---------------- K2: fused sigma + G-reduce + A = (gamma/sigma)*G@W + I ----------------
// grid = BB blocks, 256 threads. Emits bf16 A-fragments pre-swizzled for
// mfma_f32_32x32x16_bf16 A-operand: value(ks,mi,lane,j) = A[32mi+(lane&31)][16ks+(lane>>5)*8+j]
__global__ __launch_bounds__(256) void k_build_A(const float* __restrict__ W,
                                                 const float* __restrict__ u,
                                                 const float* __restrict__ gamma,
                                                 const float* __restrict__ Gp,
                                                 unsigned short* __restrict__ Afrag) {
    int b = blockIdx.x;
    int tid = threadIdx.x;
    __shared__ float Ws[4096];
    __shared__ float Gs[64 * 65];
    __shared__ float As[64 * 68];
    __shared__ float us[64];
    __shared__ float gshare;

    for (int i = tid; i < 4096; i += 256) Ws[i] = W[i];
    if (tid < 64) us[tid] = u[tid];
    __syncthreads();

    // wave 0: spectral norm (one power iteration), fold 1/sigma into gamma
    if (tid < 64) {
        int c = tid;
        float t = 0.f;
        #pragma unroll 8
        for (int r = 0; r < 64; ++r) t += Ws[r * 64 + c] * us[r];
        float s = t * t;
        #pragma unroll
        for (int m = 1; m < 64; m <<= 1) s += __shfl_xor(s, m);
        float v = t / fmaxf(sqrtf(s), 1e-12f);
        float wv = 0.f;
        #pragma unroll 8
        for (int k = 0; k < 64; ++k) wv += Ws[c * 64 + k] * __shfl(v, k);
        float s2 = wv * wv;
        #pragma unroll
        for (int m = 1; m < 64; m <<= 1) s2 += __shfl_xor(s2, m);
        float nw = sqrtf(s2);
        float sigma = s2 / fmaxf(nw, 1e-12f);
        if (c == 0) gshare = gamma[0] / fmaxf(sigma, 1e-30f);
    }

    // all threads: reduce the 32 Gram partials (coalesced)
    const float* gp = Gp + (size_t)b * NCH * 4096;
    for (int i = tid; i < 4096; i += 256) {
        float s = 0.f;
        #pragma unroll
        for (int c = 0; c < NCH; ++c) s += gp[c * 4096 + i];
        Gs[(i >> 6) * 65 + (i & 63)] = s;
    }
    __syncthreads();

    // A[r][c] = g2 * sum_k G[r][k] W[k][c] + (r==c)
    {
        int r = tid >> 2, j0 = (tid & 3) * 16;
        float a[16];
        #pragma unroll
        for (int j = 0; j < 16; ++j) a[j] = 0.f;
        for (int k = 0; k < 64; ++k) {
            float g = Gs[r * 65 + k];
            const float* wr = &Ws[k * 64 + j0];
            float4 w0 = *(const float4*)(wr);
            float4 w1 = *(const float4*)(wr + 4);
            float4 w2 = *(const float4*)(wr + 8);
            float4 w3 = *(const float4*)(wr + 12);
            a[0]  += g * w0.x; a[1]  += g * w0.y; a[2]  += g * w0.z; a[3]  += g * w0.w;
            a[4]  += g * w1.x; a[5]  += g * w1.y; a[6]  += g * w1.z; a[7]  += g * w1.w;
            a[8]  += g * w2.x; a[9]  += g * w2.y; a[10] += g * w2.z; a[11] += g * w2.w;
            a[12] += g * w3.x; a[13] += g * w3.y; a[14] += g * w3.z; a[15] += g * w3.w;
        }
        float g2 = gshare;
        #pragma unroll
        for (int j = 0; j < 16; ++j) {
            float vv = a[j] * g2 + ((r == j0 + j) ? 1.f : 0.f);
            As[r * 68 + j0 + j] = vv;
        }
    }
    __syncthreads();

    // emit pre-swizzled bf16 fragments
    unsigned short* Ab = Afrag + (size_t)b * 4096;
    for (int fv = tid; fv < 512; fv += 256) {
        int ks = fv >> 7, mi = (fv >> 6) & 1, lane = fv & 63;
        int row = 32 * mi + (lane & 31);
        int col = 16 * ks + (lane >> 5) * 8;
        float4 a4 = *(const float4*)&As[row * 68 + col];
        float4 b4 = *(const float4*)&As[row * 68 + col + 4];
        *(bf16x8*)(Ab + (size_t)fv * 8) = cvt8(a4, b4);
    }
}

// ---------------- K3: out_b = A_b @ X_b (bf16 MFMA 32x32x16) ----------------
// grid = BB*128 blocks, 256 threads (4 waves). Block tile: 64 rows x 128 cols.
// Reads f32 x (L3-resident after k_gram streamed it) and converts during staging.
#define PITCH 68  // shorts per XT row; write banks (2n+rp)%32 conflict-free, b64 reads balanced
__global__ __launch_bounds__(256) void k_out(const float* __restrict__ x,
                                             const unsigned short* __restrict__ Afrag,
                                             float* __restrict__ out) {
    int nblk = blockIdx.x & 127;
    int b = blockIdx.x >> 7;
    int col0 = nblk * 128;
    int wave = threadIdx.x >> 6, lane = threadIdx.x & 63;
    const float* xb = x + (size_t)b * CC * NN;

    __shared__ __align__(16) unsigned short XT[128 * PITCH]; // transposed tile [n][k]

    // stage + transpose: rp = row pair (0..31), nc = 16-col chunk (0..7)
    {
        int rp = threadIdx.x & 31;
        int nc = threadIdx.x >> 5;
        int r0 = rp * 2;
        int cs = nc * 16;
        const float* pr0 = xb + (size_t)r0 * NN + col0 + cs;
        const float* pr1 = pr0 + NN;
        #pragma unroll
        for (int q = 0; q < 4; ++q) {
            float4 a  = *(const float4*)(pr0 + q * 4);
            float4 b4 = *(const float4*)(pr1 + q * 4);
            const float* av = (const float*)&a;
            const float* bv = (const float*)&b4;
            #pragma unroll
            for (int e = 0; e < 4; ++e) {
                int n = cs + q * 4 + e;
                unsigned int lo = f2bf(av[e]);
                unsigned int hi = f2bf(bv[e]);
                *(unsigned int*)&XT[n * PITCH + r0] = lo | (hi << 16);
            }
        }
    }

    // A fragments (pre-swizzled): 4 k-steps x 2 m-tiles
    bf16x8 af[4][2];
    const unsigned short* Ab = Afrag + (size_t)b * 4096;
    #pragma unroll
    for (int ks = 0; ks < 4; ++ks)
        #pragma unroll
        for (int mi = 0; mi < 2; ++mi)
            af[ks][mi] = *(const bf16x8*)(Ab + ((ks * 2 + mi) * 64 + lane) * 8);

    __syncthreads();

    f32x16 acc[2] = {};
    int n = wave * 32 + (lane & 31);
    int kh = (lane >> 5) * 8;
    #pragma unroll
    for (int ks = 0; ks < 4; ++ks) {
        union { bf16x8 v; bf16x4 h[2]; } bu;
        bu.h[0] = *(const bf16x4*)&XT[n * PITCH + ks * 16 + kh];
        bu.h[1] = *(const bf16x4*)&XT[n * PITCH + ks * 16 + kh + 4];
        acc[0] = __builtin_amdgcn_mfma_f32_32x32x16_bf16(af[ks][0], bu.v, acc[0], 0, 0, 0);
        acc[1] = __builtin_amdgcn_mfma_f32_32x32x16_bf16(af[ks][1], bu.v, acc[1], 0, 0, 0);
    }

    // store: D col = lane&31, row = (reg&3) + 8*(reg>>2) + 4*(lane>>5)
    float* ob = out + (size_t)b * CC * NN;
    int gcol = col0 + n;
    #pragma unroll
    for (int mi = 0; mi < 2; ++mi)
        #pragma unroll
        for (int r = 0; r < 16; ++r) {
            int grow = 32 * mi + (r & 3) + 8 * (r >> 2) + 4 * (lane >> 5);
            ob[(size_t)grow * NN + gcol] = acc[mi][r];
        }
}

extern "C" void kernel_launch(void* const* d_in, const int* in_sizes, int n_in,
                              void* d_out, int out_size, void* d_ws, size_t ws_size,
                              hipStream_t stream) {
    const float* x     = (const float*)d_in[0];
    const float* W     = (const float*)d_in[1];
    const float* gamma = (const float*)d_in[2];
    const float* u     = (const float*)d_in[3];
    float* out = (float*)d_out;

    char* ws = (char*)d_ws;
    float* Gp             = (float*)ws;                          // 32*32*4096*4 = 16 MB
    unsigned short* Afrag = (unsigned short*)(ws + (16 << 20));  // 256 KB

    k_gram<<<BB * NCH, 512, 0, stream>>>(x, Gp);
    k_build_A<<<BB, 256, 0, stream>>>(W, u, gamma, Gp, Afrag);
    k_out<<<BB * 128, 256, 0, stream>>>(x, Afrag, out);
}